// Round 12
// baseline (1162.804 us; speedup 1.0000x reference)
//
#include <hip/hip_runtime.h>

#define HID 256
#define BT 64
#define DTC 0.05f

typedef __attribute__((ext_vector_type(4))) float f32x4;
typedef __attribute__((ext_vector_type(8))) __bf16 bf16x8;

__device__ __forceinline__ unsigned cvt_pk_bf16(float lo, float hi) {
    unsigned r;
    asm("v_cvt_pk_bf16_f32 %0, %1, %2" : "=v"(r) : "v"(lo), "v"(hi));
    return r;
}

__device__ __forceinline__ unsigned short f2bf(float f) {
    unsigned int x = __float_as_uint(f);
    x += 0x7fffu + ((x >> 16) & 1u);
    return (unsigned short)(x >> 16);
}

__device__ __forceinline__ float sgpr_f(float v) {
    return __uint_as_float(__builtin_amdgcn_readfirstlane(__float_as_uint(v)));
}

// ---------------- prepack: fragment-linearized bf16 weight buffers ----------------
#define OFF_FWDT 0         // [nt16][kk8][lane64][j8] : B[k][n]=kW2[n][k]  (fwd: a2 = h1 @ kW2^T)
#define OFF_BWDT 65536     // B[k][n]=kW2[k][n]                            (bwd: d1 = s2 @ kW2)
#define OFF_FWDV 131072
#define OFF_BWDV 196608
#define OFF_PROJT 262144   // [kk8][lane64][j8] : B[k][c]=kW1[k][c], c<3 else 0
#define OFF_PROJV 266240
#define TOTAL_PRE 270336

__global__ void prepack_kernel(const float* __restrict__ kW1, const float* __restrict__ kW2,
                               const float* __restrict__ pW1, const float* __restrict__ pW2,
                               unsigned short* __restrict__ ws) {
    int t = blockIdx.x * 256 + threadIdx.x;
    if (t >= TOTAL_PRE) return;
    float v;
    if (t < OFF_FWDV) {               // kW2 fwd/bwd
        int tt = t & 65535;
        bool bwd = t >= OFF_BWDT;
        int j = tt & 7, lane = (tt >> 3) & 63, kk = (tt >> 9) & 7, nt = tt >> 12;
        int n = nt * 16 + (lane & 15);
        int k = kk * 32 + (lane >> 4) * 8 + j;
        v = bwd ? kW2[k * HID + n] : kW2[n * HID + k];
    } else if (t < OFF_PROJT) {       // pW2 fwd/bwd
        int tt = (t - OFF_FWDV) & 65535;
        bool bwd = t >= OFF_BWDV;
        int j = tt & 7, lane = (tt >> 3) & 63, kk = (tt >> 9) & 7, nt = tt >> 12;
        int n = nt * 16 + (lane & 15);
        int k = kk * 32 + (lane >> 4) * 8 + j;
        v = bwd ? pW2[k * HID + n] : pW2[n * HID + k];
    } else if (t < OFF_PROJV) {       // kW1 projection (N=3 padded to 16)
        int tt = t - OFF_PROJT;
        int j = tt & 7, lane = (tt >> 3) & 63, kk = tt >> 9;
        int c = lane & 15;
        int k = kk * 32 + (lane >> 4) * 8 + j;
        v = (c < 3) ? kW1[k * 3 + c] : 0.f;
    } else {                          // pW1 projection (N=2 padded to 16)
        int tt = t - OFF_PROJV;
        int j = tt & 7, lane = (tt >> 3) & 63, kk = tt >> 9;
        int c = lane & 15;
        int k = kk * 32 + (lane >> 4) * 8 + j;
        v = (c < 2) ? pW1[k * 2 + c] : 0.f;
    }
    ws[t] = f2bf(v);
}

// ---------------- fused main kernel ----------------
// 512 threads = 8 waves, 64 samples/block. NET-PARALLEL: waves 0-3 run the T-net,
// waves 4-7 run the V-net CONCURRENTLY (nets are independent until the epilogue).
// Each net has its own LDS buffer pair (4 x 32KB = 131KB, 1 block/CU).
// Wave wl (= w&3) owns output cols [wl*64, wl*64+64) of its net -> acc[4][4].
// Same total work as R10, but barriers/stage 9 -> 5 and double the independent
// work per barrier interval. The instruction stream is IDENTICAL for all waves
// (V-net loads w2 = 0; proj masked by runtime nout), so the shared barriers are
// uniform: only pointer values differ per wave.
// sigma(a1) kept packed bf16 in s1p[32] regs (phase 5: no LDS read, no exp).
// kk=0 B-fragments prefetched before the barrier; next-kk loaded in-loop.
// LDS rows XOR-swizzled: byte_in_row ^= (row&7)<<4.
// MFMA 16x16x32 bf16 layouts (verified rounds 1-10, absmax 1.6e-2):
//   A: lane holds A[m=lane&15][k=(lane>>4)*8 + j]
//   B: lane holds B[k=(lane>>4)*8 + j][n=lane&15]
//   C: lane reg r holds C[m=(lane>>4)*4 + r][n=lane&15]

#define MFMA __builtin_amdgcn_mfma_f32_16x16x32_bf16

struct NetRegs { float w0[4], w1[4], w2[4], b1[4], b2[4], w3[4]; };

__device__ __forceinline__ void run_net(
    char* bufAc, char* bufBc,
    const float* sh_sin, const float* sh_cos, const float* sh_pv,
    const NetRegs& R,
    const unsigned short* __restrict__ fwdB, const unsigned short* __restrict__ bwdB,
    const unsigned short* __restrict__ projB,
    float* g0, float* g1, float* g2, int nout,
    int wl, int lane)
{
    const int lr = lane & 15;
    const int lg = lane >> 4;
    const unsigned int arx = (unsigned)(lr & 7) << 4;
    const unsigned int cbase = ((unsigned)lg << 4) ^ arx;

    unsigned s1p[32];   // packed bf16 sigma(a1): [(mt*4+r)*2 + nt/2]

    // ---- phase 1: a1 = W1·x + b1 ; h1 = softplus -> bufA ; sigma -> s1p ----
#pragma unroll
    for (int mt = 0; mt < 4; ++mt) {
#pragma unroll
        for (int r = 0; r < 4; ++r) {
            int row = mt * 16 + lg * 4 + r;
            float sv = sh_sin[row], cv = sh_cos[row], pv = sh_pv[row];
            unsigned int rowx = (unsigned)(row & 7) << 4;
            char* rowp = bufAc + row * 512;
            float sp[4], sg[4];
#pragma unroll
            for (int nt = 0; nt < 4; ++nt) {
                float x = fmaf(R.w0[nt], sv, R.b1[nt]);
                x = fmaf(R.w1[nt], cv, x);
                x = fmaf(R.w2[nt], pv, x);      // w2 == 0 for the V-net
                float e = __expf(-fabsf(x));
                sp[nt] = fmaxf(x, 0.f) + __logf(1.f + e);
                float t = __builtin_amdgcn_rcpf(1.f + e);
                sg[nt] = (x < 0.f) ? e * t : t;
            }
            unsigned d01 = cvt_pk_bf16(sp[0], sp[1]);
            unsigned d23 = cvt_pk_bf16(sp[2], sp[3]);
            int j0 = wl * 64 + lr;
            *(unsigned short*)(rowp + (((j0 +  0) * 2) ^ rowx)) = (unsigned short)d01;
            *(unsigned short*)(rowp + (((j0 + 16) * 2) ^ rowx)) = (unsigned short)(d01 >> 16);
            *(unsigned short*)(rowp + (((j0 + 32) * 2) ^ rowx)) = (unsigned short)d23;
            *(unsigned short*)(rowp + (((j0 + 48) * 2) ^ rowx)) = (unsigned short)(d23 >> 16);
            s1p[(mt * 4 + r) * 2 + 0] = cvt_pk_bf16(sg[0], sg[1]);
            s1p[(mt * 4 + r) * 2 + 1] = cvt_pk_bf16(sg[2], sg[3]);
        }
    }

    // prefetch kk=0 fwd B-fragments (global, no LDS dependency) before barrier
    const unsigned short* fb = fwdB + (wl * 4) * 8 * 512 + lane * 8;
    bf16x8 c0 = *(const bf16x8*)(fb + 0 * 512);
    bf16x8 c1 = *(const bf16x8*)(fb + 8 * 512);
    bf16x8 c2 = *(const bf16x8*)(fb + 16 * 512);
    bf16x8 c3 = *(const bf16x8*)(fb + 24 * 512);
    __syncthreads();   // h1 visible (both nets)

    // ---- phase 2: fwd GEMM  acc = H1 @ W2^T  (reads bufA) ----
    f32x4 acc[4][4];
#pragma unroll
    for (int mt = 0; mt < 4; ++mt)
#pragma unroll
        for (int nt = 0; nt < 4; ++nt)
            acc[mt][nt] = (f32x4){0.f, 0.f, 0.f, 0.f};
    {
#pragma unroll 1
        for (int kk = 0; kk < 8; ++kk) {
            unsigned int off = cbase ^ (unsigned)(kk << 6);
            bf16x8 af0 = *(const bf16x8*)(bufAc + (0 * 16 + lr) * 512 + off);
            bf16x8 af1 = *(const bf16x8*)(bufAc + (1 * 16 + lr) * 512 + off);
            bf16x8 af2 = *(const bf16x8*)(bufAc + (2 * 16 + lr) * 512 + off);
            bf16x8 af3 = *(const bf16x8*)(bufAc + (3 * 16 + lr) * 512 + off);
            acc[0][0] = MFMA(af0, c0, acc[0][0], 0, 0, 0);
            acc[0][1] = MFMA(af0, c1, acc[0][1], 0, 0, 0);
            acc[0][2] = MFMA(af0, c2, acc[0][2], 0, 0, 0);
            acc[0][3] = MFMA(af0, c3, acc[0][3], 0, 0, 0);
            acc[1][0] = MFMA(af1, c0, acc[1][0], 0, 0, 0);
            acc[1][1] = MFMA(af1, c1, acc[1][1], 0, 0, 0);
            acc[1][2] = MFMA(af1, c2, acc[1][2], 0, 0, 0);
            acc[1][3] = MFMA(af1, c3, acc[1][3], 0, 0, 0);
            acc[2][0] = MFMA(af2, c0, acc[2][0], 0, 0, 0);
            acc[2][1] = MFMA(af2, c1, acc[2][1], 0, 0, 0);
            acc[2][2] = MFMA(af2, c2, acc[2][2], 0, 0, 0);
            acc[2][3] = MFMA(af2, c3, acc[2][3], 0, 0, 0);
            acc[3][0] = MFMA(af3, c0, acc[3][0], 0, 0, 0);
            acc[3][1] = MFMA(af3, c1, acc[3][1], 0, 0, 0);
            acc[3][2] = MFMA(af3, c2, acc[3][2], 0, 0, 0);
            acc[3][3] = MFMA(af3, c3, acc[3][3], 0, 0, 0);
            if (kk < 7) {
                c0 = *(const bf16x8*)(fb + (0 * 8 + kk + 1) * 512);
                c1 = *(const bf16x8*)(fb + (1 * 8 + kk + 1) * 512);
                c2 = *(const bf16x8*)(fb + (2 * 8 + kk + 1) * 512);
                c3 = *(const bf16x8*)(fb + (3 * 8 + kk + 1) * 512);
            }
        }
    }

    // ---- phase 3: s2 = W3 ⊙ σ(a2 + b2) -> bufB ----
#pragma unroll
    for (int nt = 0; nt < 4; ++nt) {
        int i = wl * 64 + nt * 16 + lr;
#pragma unroll
        for (int mt = 0; mt < 4; ++mt) {
            float val[4];
#pragma unroll
            for (int r = 0; r < 4; ++r) {
                float x = acc[mt][nt][r] + R.b2[nt];
                float e = __expf(-fabsf(x));
                float t = __builtin_amdgcn_rcpf(1.f + e);
                float sg = (x < 0.f) ? e * t : t;
                val[r] = R.w3[nt] * sg;
            }
            unsigned d01 = cvt_pk_bf16(val[0], val[1]);
            unsigned d23 = cvt_pk_bf16(val[2], val[3]);
#pragma unroll
            for (int r = 0; r < 4; ++r) {
                int row = mt * 16 + lg * 4 + r;
                unsigned short hv = (r == 0) ? (unsigned short)d01
                                  : (r == 1) ? (unsigned short)(d01 >> 16)
                                  : (r == 2) ? (unsigned short)d23
                                             : (unsigned short)(d23 >> 16);
                *(unsigned short*)(bufBc + row * 512 + ((i * 2) ^ ((unsigned)(row & 7) << 4))) = hv;
            }
        }
    }

    // prefetch kk=0 bwd B-fragments before barrier
    const unsigned short* bb = bwdB + (wl * 4) * 8 * 512 + lane * 8;
    c0 = *(const bf16x8*)(bb + 0 * 512);
    c1 = *(const bf16x8*)(bb + 8 * 512);
    c2 = *(const bf16x8*)(bb + 16 * 512);
    c3 = *(const bf16x8*)(bb + 24 * 512);
    __syncthreads();   // s2 visible

    // ---- phase 4: bwd GEMM  acc = S2 @ W2  (reads bufB) ----
#pragma unroll
    for (int mt = 0; mt < 4; ++mt)
#pragma unroll
        for (int nt = 0; nt < 4; ++nt)
            acc[mt][nt] = (f32x4){0.f, 0.f, 0.f, 0.f};
    {
#pragma unroll 1
        for (int kk = 0; kk < 8; ++kk) {
            unsigned int off = cbase ^ (unsigned)(kk << 6);
            bf16x8 af0 = *(const bf16x8*)(bufBc + (0 * 16 + lr) * 512 + off);
            bf16x8 af1 = *(const bf16x8*)(bufBc + (1 * 16 + lr) * 512 + off);
            bf16x8 af2 = *(const bf16x8*)(bufBc + (2 * 16 + lr) * 512 + off);
            bf16x8 af3 = *(const bf16x8*)(bufBc + (3 * 16 + lr) * 512 + off);
            acc[0][0] = MFMA(af0, c0, acc[0][0], 0, 0, 0);
            acc[0][1] = MFMA(af0, c1, acc[0][1], 0, 0, 0);
            acc[0][2] = MFMA(af0, c2, acc[0][2], 0, 0, 0);
            acc[0][3] = MFMA(af0, c3, acc[0][3], 0, 0, 0);
            acc[1][0] = MFMA(af1, c0, acc[1][0], 0, 0, 0);
            acc[1][1] = MFMA(af1, c1, acc[1][1], 0, 0, 0);
            acc[1][2] = MFMA(af1, c2, acc[1][2], 0, 0, 0);
            acc[1][3] = MFMA(af1, c3, acc[1][3], 0, 0, 0);
            acc[2][0] = MFMA(af2, c0, acc[2][0], 0, 0, 0);
            acc[2][1] = MFMA(af2, c1, acc[2][1], 0, 0, 0);
            acc[2][2] = MFMA(af2, c2, acc[2][2], 0, 0, 0);
            acc[2][3] = MFMA(af2, c3, acc[2][3], 0, 0, 0);
            acc[3][0] = MFMA(af3, c0, acc[3][0], 0, 0, 0);
            acc[3][1] = MFMA(af3, c1, acc[3][1], 0, 0, 0);
            acc[3][2] = MFMA(af3, c2, acc[3][2], 0, 0, 0);
            acc[3][3] = MFMA(af3, c3, acc[3][3], 0, 0, 0);
            if (kk < 7) {
                c0 = *(const bf16x8*)(bb + (0 * 8 + kk + 1) * 512);
                c1 = *(const bf16x8*)(bb + (1 * 8 + kk + 1) * 512);
                c2 = *(const bf16x8*)(bb + (2 * 8 + kk + 1) * 512);
                c3 = *(const bf16x8*)(bb + (3 * 8 + kk + 1) * 512);
            }
        }
    }

    // ---- phase 5: da1 = D1 ⊙ σ(a1) -> bufA (σ from s1p regs: no read, no exp) ----
#pragma unroll
    for (int mt = 0; mt < 4; ++mt) {
#pragma unroll
        for (int r = 0; r < 4; ++r) {
            int row = mt * 16 + lg * 4 + r;
            unsigned int rowx = (unsigned)(row & 7) << 4;
            char* rowp = bufAc + row * 512;
            unsigned pa = s1p[(mt * 4 + r) * 2 + 0];
            unsigned pb = s1p[(mt * 4 + r) * 2 + 1];
            float sg0 = __uint_as_float(pa << 16);
            float sg1 = __uint_as_float(pa & 0xffff0000u);
            float sg2 = __uint_as_float(pb << 16);
            float sg3 = __uint_as_float(pb & 0xffff0000u);
            unsigned d01 = cvt_pk_bf16(acc[mt][0][r] * sg0, acc[mt][1][r] * sg1);
            unsigned d23 = cvt_pk_bf16(acc[mt][2][r] * sg2, acc[mt][3][r] * sg3);
            int j0 = wl * 64 + lr;
            *(unsigned short*)(rowp + (((j0 +  0) * 2) ^ rowx)) = (unsigned short)d01;
            *(unsigned short*)(rowp + (((j0 + 16) * 2) ^ rowx)) = (unsigned short)(d01 >> 16);
            *(unsigned short*)(rowp + (((j0 + 32) * 2) ^ rowx)) = (unsigned short)d23;
            *(unsigned short*)(rowp + (((j0 + 48) * 2) ^ rowx)) = (unsigned short)(d23 >> 16);
        }
    }
    __syncthreads();   // da1 visible

    // ---- phase 6: projection  g = dA1 @ W1  (wave wl handles rows [wl*16,wl*16+16)) ----
    {
        const unsigned short* pb = projB + lane * 8;
        f32x4 pacc = (f32x4){0.f, 0.f, 0.f, 0.f};
        char* arow = bufAc + (wl * 16 + lr) * 512;
#pragma unroll 1
        for (int kk = 0; kk < 8; ++kk) {
            bf16x8 bv = *(const bf16x8*)(pb + kk * 512);
            bf16x8 af = *(const bf16x8*)(arow + (cbase ^ (unsigned)(kk << 6)));
            pacc = MFMA(af, bv, pacc, 0, 0, 0);
        }
        if (lr < nout) {
            float* dst = (lr == 0) ? g0 : ((lr == 1) ? g1 : g2);
#pragma unroll
            for (int r = 0; r < 4; ++r) dst[wl * 16 + lg * 4 + r] = pacc[r];
        }
    }
    __syncthreads();   // proj reads of bufA done; gradients visible
}

__global__ __launch_bounds__(512, 2) void phgn_kernel(
    const float* __restrict__ q, const float* __restrict__ p, const float* __restrict__ u,
    const float* __restrict__ kW1, const float* __restrict__ kb1,
    const float* __restrict__ kb2, const float* __restrict__ kW3,
    const float* __restrict__ pW1, const float* __restrict__ pb1,
    const float* __restrict__ pb2, const float* __restrict__ pW3,
    const float* __restrict__ A, const float* __restrict__ Lp, const float* __restrict__ bctrl,
    const unsigned short* __restrict__ ws, float* __restrict__ out)
{
    __shared__ __attribute__((aligned(16))) unsigned short bufTA[BT * HID];
    __shared__ __attribute__((aligned(16))) unsigned short bufTB[BT * HID];
    __shared__ __attribute__((aligned(16))) unsigned short bufVA[BT * HID];
    __shared__ __attribute__((aligned(16))) unsigned short bufVB[BT * HID];
    __shared__ float sh_sin[BT], sh_cos[BT], sh_pv[BT];
    __shared__ float gx0[BT], gx1[BT], gx2[BT], ge0[BT], ge1[BT];

    const int tid = threadIdx.x;
    const int w = tid >> 6, lane = tid & 63;
    const int wl = w & 3;
    const bool isV = w >= 4;
    const int lr = lane & 15;
    const int base = blockIdx.x * BT;

    // Per-wave net binding: pointer values differ, instruction stream identical.
    char* myA = isV ? (char*)bufVA : (char*)bufTA;
    char* myB = isV ? (char*)bufVB : (char*)bufTB;
    const unsigned short* myFwd  = ws + (isV ? OFF_FWDV  : OFF_FWDT);
    const unsigned short* myBwd  = ws + (isV ? OFF_BWDV  : OFF_BWDT);
    const unsigned short* myProj = ws + (isV ? OFF_PROJV : OFF_PROJT);
    float* g0 = isV ? ge0 : gx0;
    float* g1 = isV ? ge1 : gx1;
    float* g2 = isV ? ge1 : gx2;
    const int nout = isV ? 2 : 3;

    // Persistent per-thread weights for THIS wave's net (w2 = 0 for the V-net).
    NetRegs R;
#pragma unroll
    for (int nt = 0; nt < 4; ++nt) {
        int j = wl * 64 + nt * 16 + lr;
        if (!isV) {
            R.w0[nt] = kW1[j * 3 + 0];
            R.w1[nt] = kW1[j * 3 + 1];
            R.w2[nt] = kW1[j * 3 + 2];
            R.b1[nt] = kb1[j];
            R.b2[nt] = kb2[j];
            R.w3[nt] = kW3[j];
        } else {
            R.w0[nt] = pW1[j * 2 + 0];
            R.w1[nt] = pW1[j * 2 + 1];
            R.w2[nt] = 0.f;
            R.b1[nt] = pb1[j];
            R.b2[nt] = pb2[j];
            R.w3[nt] = pW3[j];
        }
    }

    // M = (A - A^T) - L L^T (uniform; pinned to SGPR via readfirstlane)
    float l00 = __logf(1.f + __expf(Lp[0]));
    float l11 = __logf(1.f + __expf(Lp[3]));
    float l10 = Lp[2];
    float J01 = A[1] - A[2];
    float M00 = sgpr_f(-(l00 * l00));
    float M01 = sgpr_f(J01 - l00 * l10);
    float M10 = sgpr_f(-J01 - l10 * l00);
    float M11 = sgpr_f(-(l10 * l10 + l11 * l11));

    float q0 = 0.f, p0 = 0.f, buv = 0.f, aq = 0.f, ap = 0.f;
    if (tid < BT) {
        q0 = q[base + tid]; p0 = p[base + tid]; buv = u[base + tid] * bctrl[0];
        float s, c; __sincosf(q0, &s, &c);
        sh_sin[tid] = s; sh_cos[tid] = c; sh_pv[tid] = p0;
    }
    __syncthreads();

#pragma unroll 1
    for (int s = 0; s < 4; ++s) {
        run_net(myA, myB, sh_sin, sh_cos, sh_pv, R,
                myFwd, myBwd, myProj, g0, g1, g2, nout, wl, lane);
        if (tid < BT) {
            float gq = (gx0[tid] + ge0[tid]) * sh_cos[tid] - (gx1[tid] + ge1[tid]) * sh_sin[tid];
            float gp = gx2[tid];
            float dq = M00 * gq + M01 * gp;
            float dp = M10 * gq + M11 * gp + buv;
            float wgt = (s == 0 || s == 3) ? 1.f : 2.f;
            aq += wgt * dq; ap += wgt * dp;
            if (s < 3) {
                float cs = (s == 2) ? 1.f : 0.5f;
                float qs = fmaf(cs * DTC, dq, q0);
                float ps = fmaf(cs * DTC, dp, p0);
                float sn, cn; __sincosf(qs, &sn, &cn);
                sh_sin[tid] = sn; sh_cos[tid] = cn; sh_pv[tid] = ps;
            } else {
                float qn = fmaf(DTC / 6.f, aq, q0);
                float pn = fmaf(DTC / 6.f, ap, p0);
                ((float2*)out)[base + tid] = make_float2(qn, pn);
            }
        }
        __syncthreads();
    }
}

extern "C" void kernel_launch(void* const* d_in, const int* in_sizes, int n_in,
                              void* d_out, int out_size, void* d_ws, size_t ws_size,
                              hipStream_t stream) {
    const float* q    = (const float*)d_in[0];
    const float* p    = (const float*)d_in[1];
    const float* u    = (const float*)d_in[2];
    const float* kW1  = (const float*)d_in[3];
    const float* kb1  = (const float*)d_in[4];
    const float* kW2  = (const float*)d_in[5];
    const float* kb2  = (const float*)d_in[6];
    const float* kW3  = (const float*)d_in[7];
    const float* pW1  = (const float*)d_in[9];
    const float* pb1  = (const float*)d_in[10];
    const float* pW2  = (const float*)d_in[11];
    const float* pb2  = (const float*)d_in[12];
    const float* pW3  = (const float*)d_in[13];
    const float* A    = (const float*)d_in[15];
    const float* Lp   = (const float*)d_in[16];
    const float* bctl = (const float*)d_in[17];
    unsigned short* ws = (unsigned short*)d_ws;
    float* out = (float*)d_out;
    int B = in_sizes[0];

    prepack_kernel<<<(TOTAL_PRE + 255) / 256, 256, 0, stream>>>(kW1, kW2, pW1, pW2, ws);
    phgn_kernel<<<B / BT, 512, 0, stream>>>(q, p, u, kW1, kb1, kb2, kW3,
                                            pW1, pb1, pb2, pW3, A, Lp, bctl, ws, out);
}

// Round 13
// 807.194 us; speedup vs baseline: 1.4406x; 1.4406x over previous
//
#include <hip/hip_runtime.h>

#define HID 256
#define BT 64
#define DTC 0.05f

typedef __attribute__((ext_vector_type(4))) float f32x4;
typedef __attribute__((ext_vector_type(8))) __bf16 bf16x8;

__device__ __forceinline__ unsigned cvt_pk_bf16(float lo, float hi) {
    unsigned r;
    asm("v_cvt_pk_bf16_f32 %0, %1, %2" : "=v"(r) : "v"(lo), "v"(hi));
    return r;
}

__device__ __forceinline__ unsigned short f2bf(float f) {
    unsigned int x = __float_as_uint(f);
    x += 0x7fffu + ((x >> 16) & 1u);
    return (unsigned short)(x >> 16);
}

__device__ __forceinline__ float sgpr_f(float v) {
    return __uint_as_float(__builtin_amdgcn_readfirstlane(__float_as_uint(v)));
}

// ---------------- prepack: fragment-linearized bf16 weight buffers ----------------
#define OFF_FWDT 0         // [nt16][kk8][lane64][j8] : B[k][n]=kW2[n][k]  (fwd: a2 = h1 @ kW2^T)
#define OFF_BWDT 65536     // B[k][n]=kW2[k][n]                            (bwd: d1 = s2 @ kW2)
#define OFF_FWDV 131072
#define OFF_BWDV 196608
#define OFF_PROJT 262144   // [kk8][lane64][j8] : B[k][c]=kW1[k][c], c<3 else 0
#define OFF_PROJV 266240
#define TOTAL_PRE 270336

__global__ void prepack_kernel(const float* __restrict__ kW1, const float* __restrict__ kW2,
                               const float* __restrict__ pW1, const float* __restrict__ pW2,
                               unsigned short* __restrict__ ws) {
    int t = blockIdx.x * 256 + threadIdx.x;
    if (t >= TOTAL_PRE) return;
    float v;
    if (t < OFF_FWDV) {               // kW2 fwd/bwd
        int tt = t & 65535;
        bool bwd = t >= OFF_BWDT;
        int j = tt & 7, lane = (tt >> 3) & 63, kk = (tt >> 9) & 7, nt = tt >> 12;
        int n = nt * 16 + (lane & 15);
        int k = kk * 32 + (lane >> 4) * 8 + j;
        v = bwd ? kW2[k * HID + n] : kW2[n * HID + k];
    } else if (t < OFF_PROJT) {       // pW2 fwd/bwd
        int tt = (t - OFF_FWDV) & 65535;
        bool bwd = t >= OFF_BWDV;
        int j = tt & 7, lane = (tt >> 3) & 63, kk = (tt >> 9) & 7, nt = tt >> 12;
        int n = nt * 16 + (lane & 15);
        int k = kk * 32 + (lane >> 4) * 8 + j;
        v = bwd ? pW2[k * HID + n] : pW2[n * HID + k];
    } else if (t < OFF_PROJV) {       // kW1 projection (N=3 padded to 16)
        int tt = t - OFF_PROJT;
        int j = tt & 7, lane = (tt >> 3) & 63, kk = tt >> 9;
        int c = lane & 15;
        int k = kk * 32 + (lane >> 4) * 8 + j;
        v = (c < 3) ? kW1[k * 3 + c] : 0.f;
    } else {                          // pW1 projection (N=2 padded to 16)
        int tt = t - OFF_PROJV;
        int j = tt & 7, lane = (tt >> 3) & 63, kk = tt >> 9;
        int c = lane & 15;
        int k = kk * 32 + (lane >> 4) * 8 + j;
        v = (c < 2) ? pW1[k * 2 + c] : 0.f;
    }
    ws[t] = f2bf(v);
}

// ---------------- fused main kernel ----------------
// 1024 threads = 16 waves, 64 samples/block. Wave w = (wm,wn) = (w>>3, w&7) owns a
// 32x32 output tile: rows [wm*32,wm*32+32), cols [wn*32,wn*32+32) -> acc[2][2] =
// 16 AGPRs. Per-wave register demand ~90 unified <= 128 cap from
// __launch_bounds__(1024,4) -> 4 waves/SIMD (2x R10's TLP), spill-free.
// Rationale: R12 proved acc[4][4]+s1p[32]+prefetch > 256 cap -> 340MB spill;
// R10 sat at 150 regs wasting the 2-waves/SIMD tier. This shape moves DOWN the
// m69 occupancy staircase (<=128 regs -> 4 waves/SIMD) instead of up.
// Nets run sequentially (T then V) like R10; af:MFMA LDS ratio unchanged.
// sigma(a1) packed bf16 in s1p[8] regs; kk=0 B-fragments prefetched pre-barrier.
// LDS rows XOR-swizzled: byte_in_row ^= (row&7)<<4.
// MFMA 16x16x32 bf16 layouts (verified rounds 1-12, absmax 1.6e-2):
//   A: lane holds A[m=lane&15][k=(lane>>4)*8 + j]
//   B: lane holds B[k=(lane>>4)*8 + j][n=lane&15]
//   C: lane reg r holds C[m=(lane>>4)*4 + r][n=lane&15]

#define MFMA __builtin_amdgcn_mfma_f32_16x16x32_bf16

struct NetRegs { float w0[2], w1[2], w2[2], b1[2], b2[2], w3[2]; };

template <int IND, int NOUT>
__device__ __forceinline__ void run_net(
    char* bufAc, char* bufBc,
    const float* sh_sin, const float* sh_cos, const float* sh_pv,
    const NetRegs& R,
    const unsigned short* __restrict__ fwdB, const unsigned short* __restrict__ bwdB,
    const unsigned short* __restrict__ projB,
    float* g0, float* g1, float* g2,
    int wm, int wn, int w, int lane)
{
    const int lr = lane & 15;
    const int lg = lane >> 4;
    const unsigned int arx = (unsigned)(lr & 7) << 4;
    const unsigned int cbase = ((unsigned)lg << 4) ^ arx;

    unsigned s1p[8];   // packed bf16 sigma(a1): [mt*4 + r], pairs (nt0, nt1)

    // ---- phase 1: a1 = W1·x + b1 ; h1 = softplus -> bufA ; sigma -> s1p ----
#pragma unroll
    for (int mt = 0; mt < 2; ++mt) {
#pragma unroll
        for (int r = 0; r < 4; ++r) {
            int row = wm * 32 + mt * 16 + lg * 4 + r;
            float sv = sh_sin[row], cv = sh_cos[row];
            float pv = (IND == 3) ? sh_pv[row] : 0.f;
            unsigned int rowx = (unsigned)(row & 7) << 4;
            char* rowp = bufAc + row * 512;
            float sp[2], sg[2];
#pragma unroll
            for (int nt = 0; nt < 2; ++nt) {
                float x = fmaf(R.w0[nt], sv, R.b1[nt]);
                x = fmaf(R.w1[nt], cv, x);
                if (IND == 3) x = fmaf(R.w2[nt], pv, x);
                float e = __expf(-fabsf(x));
                sp[nt] = fmaxf(x, 0.f) + __logf(1.f + e);
                float t = __builtin_amdgcn_rcpf(1.f + e);
                sg[nt] = (x < 0.f) ? e * t : t;
            }
            unsigned d01 = cvt_pk_bf16(sp[0], sp[1]);
            int j0 = wn * 32 + lr;
            *(unsigned short*)(rowp + (((j0 +  0) * 2) ^ rowx)) = (unsigned short)d01;
            *(unsigned short*)(rowp + (((j0 + 16) * 2) ^ rowx)) = (unsigned short)(d01 >> 16);
            s1p[mt * 4 + r] = cvt_pk_bf16(sg[0], sg[1]);
        }
    }

    // prefetch kk=0 fwd B-fragments (global, no LDS dependency) before barrier
    const unsigned short* fb = fwdB + (wn * 2) * 8 * 512 + lane * 8;
    bf16x8 c0 = *(const bf16x8*)(fb + 0 * 512);
    bf16x8 c1 = *(const bf16x8*)(fb + 8 * 512);
    __syncthreads();   // h1 visible

    // ---- phase 2: fwd GEMM  acc = H1 @ W2^T  (reads bufA) ----
    f32x4 acc[2][2];
#pragma unroll
    for (int mt = 0; mt < 2; ++mt)
#pragma unroll
        for (int nt = 0; nt < 2; ++nt)
            acc[mt][nt] = (f32x4){0.f, 0.f, 0.f, 0.f};
    {
#pragma unroll 1
        for (int kk = 0; kk < 8; ++kk) {
            unsigned int off = cbase ^ (unsigned)(kk << 6);
            bf16x8 af0 = *(const bf16x8*)(bufAc + (wm * 32 +  0 + lr) * 512 + off);
            bf16x8 af1 = *(const bf16x8*)(bufAc + (wm * 32 + 16 + lr) * 512 + off);
            acc[0][0] = MFMA(af0, c0, acc[0][0], 0, 0, 0);
            acc[0][1] = MFMA(af0, c1, acc[0][1], 0, 0, 0);
            acc[1][0] = MFMA(af1, c0, acc[1][0], 0, 0, 0);
            acc[1][1] = MFMA(af1, c1, acc[1][1], 0, 0, 0);
            if (kk < 7) {
                c0 = *(const bf16x8*)(fb + (0 * 8 + kk + 1) * 512);
                c1 = *(const bf16x8*)(fb + (1 * 8 + kk + 1) * 512);
            }
        }
    }

    // ---- phase 3: s2 = W3 ⊙ σ(a2 + b2) -> bufB ----
#pragma unroll
    for (int nt = 0; nt < 2; ++nt) {
        int i = wn * 32 + nt * 16 + lr;
#pragma unroll
        for (int mt = 0; mt < 2; ++mt) {
            float val[4];
#pragma unroll
            for (int r = 0; r < 4; ++r) {
                float x = acc[mt][nt][r] + R.b2[nt];
                float e = __expf(-fabsf(x));
                float t = __builtin_amdgcn_rcpf(1.f + e);
                float sg = (x < 0.f) ? e * t : t;
                val[r] = R.w3[nt] * sg;
            }
            unsigned d01 = cvt_pk_bf16(val[0], val[1]);
            unsigned d23 = cvt_pk_bf16(val[2], val[3]);
#pragma unroll
            for (int r = 0; r < 4; ++r) {
                int row = wm * 32 + mt * 16 + lg * 4 + r;
                unsigned short hv = (r == 0) ? (unsigned short)d01
                                  : (r == 1) ? (unsigned short)(d01 >> 16)
                                  : (r == 2) ? (unsigned short)d23
                                             : (unsigned short)(d23 >> 16);
                *(unsigned short*)(bufBc + row * 512 + ((i * 2) ^ ((unsigned)(row & 7) << 4))) = hv;
            }
        }
    }

    // prefetch kk=0 bwd B-fragments before barrier
    const unsigned short* bb = bwdB + (wn * 2) * 8 * 512 + lane * 8;
    c0 = *(const bf16x8*)(bb + 0 * 512);
    c1 = *(const bf16x8*)(bb + 8 * 512);
    __syncthreads();   // s2 visible

    // ---- phase 4: bwd GEMM  acc = S2 @ W2  (reads bufB) ----
#pragma unroll
    for (int mt = 0; mt < 2; ++mt)
#pragma unroll
        for (int nt = 0; nt < 2; ++nt)
            acc[mt][nt] = (f32x4){0.f, 0.f, 0.f, 0.f};
    {
#pragma unroll 1
        for (int kk = 0; kk < 8; ++kk) {
            unsigned int off = cbase ^ (unsigned)(kk << 6);
            bf16x8 af0 = *(const bf16x8*)(bufBc + (wm * 32 +  0 + lr) * 512 + off);
            bf16x8 af1 = *(const bf16x8*)(bufBc + (wm * 32 + 16 + lr) * 512 + off);
            acc[0][0] = MFMA(af0, c0, acc[0][0], 0, 0, 0);
            acc[0][1] = MFMA(af0, c1, acc[0][1], 0, 0, 0);
            acc[1][0] = MFMA(af1, c0, acc[1][0], 0, 0, 0);
            acc[1][1] = MFMA(af1, c1, acc[1][1], 0, 0, 0);
            if (kk < 7) {
                c0 = *(const bf16x8*)(bb + (0 * 8 + kk + 1) * 512);
                c1 = *(const bf16x8*)(bb + (1 * 8 + kk + 1) * 512);
            }
        }
    }

    // ---- phase 5: da1 = D1 ⊙ σ(a1) -> bufA (σ from s1p regs: no read, no exp) ----
#pragma unroll
    for (int mt = 0; mt < 2; ++mt) {
#pragma unroll
        for (int r = 0; r < 4; ++r) {
            int row = wm * 32 + mt * 16 + lg * 4 + r;
            unsigned int rowx = (unsigned)(row & 7) << 4;
            char* rowp = bufAc + row * 512;
            unsigned pa = s1p[mt * 4 + r];
            float sg0 = __uint_as_float(pa << 16);
            float sg1 = __uint_as_float(pa & 0xffff0000u);
            unsigned d01 = cvt_pk_bf16(acc[mt][0][r] * sg0, acc[mt][1][r] * sg1);
            int j0 = wn * 32 + lr;
            *(unsigned short*)(rowp + (((j0 +  0) * 2) ^ rowx)) = (unsigned short)d01;
            *(unsigned short*)(rowp + (((j0 + 16) * 2) ^ rowx)) = (unsigned short)(d01 >> 16);
        }
    }
    __syncthreads();   // da1 visible

    // ---- phase 6: projection  g = dA1 @ W1  (waves 0-3, rows [w*16,w*16+16)) ----
    if (w < 4) {
        const unsigned short* pb = projB + lane * 8;
        f32x4 pacc = (f32x4){0.f, 0.f, 0.f, 0.f};
        char* arow = bufAc + (w * 16 + lr) * 512;
#pragma unroll 1
        for (int kk = 0; kk < 8; ++kk) {
            bf16x8 bv = *(const bf16x8*)(pb + kk * 512);
            bf16x8 af = *(const bf16x8*)(arow + (cbase ^ (unsigned)(kk << 6)));
            pacc = MFMA(af, bv, pacc, 0, 0, 0);
        }
        if (lr < NOUT) {
            float* dst = (lr == 0) ? g0 : ((lr == 1) ? g1 : g2);
#pragma unroll
            for (int r = 0; r < 4; ++r) dst[w * 16 + lg * 4 + r] = pacc[r];
        }
    }
    __syncthreads();   // proj reads of bufA done; gradients visible
}

__global__ __launch_bounds__(1024, 4) void phgn_kernel(
    const float* __restrict__ q, const float* __restrict__ p, const float* __restrict__ u,
    const float* __restrict__ kW1, const float* __restrict__ kb1,
    const float* __restrict__ kb2, const float* __restrict__ kW3,
    const float* __restrict__ pW1, const float* __restrict__ pb1,
    const float* __restrict__ pb2, const float* __restrict__ pW3,
    const float* __restrict__ A, const float* __restrict__ Lp, const float* __restrict__ bctrl,
    const unsigned short* __restrict__ ws, float* __restrict__ out)
{
    __shared__ __attribute__((aligned(16))) unsigned short bufA[BT * HID];
    __shared__ __attribute__((aligned(16))) unsigned short bufB[BT * HID];
    __shared__ float sh_sin[BT], sh_cos[BT], sh_pv[BT];
    __shared__ float gx0[BT], gx1[BT], gx2[BT], ge0[BT], ge1[BT];

    const int tid = threadIdx.x;
    const int w = tid >> 6, lane = tid & 63;
    const int wm = w >> 3, wn = w & 7;
    const int lr = lane & 15;
    const int base = blockIdx.x * BT;

    // Persistent per-thread weights (stage-invariant), loaded once.
    NetRegs RT, RV;
#pragma unroll
    for (int nt = 0; nt < 2; ++nt) {
        int j = wn * 32 + nt * 16 + lr;
        RT.w0[nt] = kW1[j * 3 + 0];
        RT.w1[nt] = kW1[j * 3 + 1];
        RT.w2[nt] = kW1[j * 3 + 2];
        RT.b1[nt] = kb1[j];
        RT.b2[nt] = kb2[j];
        RT.w3[nt] = kW3[j];
        RV.w0[nt] = pW1[j * 2 + 0];
        RV.w1[nt] = pW1[j * 2 + 1];
        RV.w2[nt] = 0.f;
        RV.b1[nt] = pb1[j];
        RV.b2[nt] = pb2[j];
        RV.w3[nt] = pW3[j];
    }

    // M = (A - A^T) - L L^T (uniform; pinned to SGPR via readfirstlane)
    float l00 = __logf(1.f + __expf(Lp[0]));
    float l11 = __logf(1.f + __expf(Lp[3]));
    float l10 = Lp[2];
    float J01 = A[1] - A[2];
    float M00 = sgpr_f(-(l00 * l00));
    float M01 = sgpr_f(J01 - l00 * l10);
    float M10 = sgpr_f(-J01 - l10 * l00);
    float M11 = sgpr_f(-(l10 * l10 + l11 * l11));

    float q0 = 0.f, p0 = 0.f, buv = 0.f, aq = 0.f, ap = 0.f;
    if (tid < BT) {
        q0 = q[base + tid]; p0 = p[base + tid]; buv = u[base + tid] * bctrl[0];
        float s, c; __sincosf(q0, &s, &c);
        sh_sin[tid] = s; sh_cos[tid] = c; sh_pv[tid] = p0;
    }
    __syncthreads();

    char* bufAc = (char*)bufA;
    char* bufBc = (char*)bufB;
#pragma unroll 1
    for (int s = 0; s < 4; ++s) {
        run_net<3, 3>(bufAc, bufBc, sh_sin, sh_cos, sh_pv, RT,
                      ws + OFF_FWDT, ws + OFF_BWDT, ws + OFF_PROJT, gx0, gx1, gx2, wm, wn, w, lane);
        run_net<2, 2>(bufAc, bufBc, sh_sin, sh_cos, sh_pv, RV,
                      ws + OFF_FWDV, ws + OFF_BWDV, ws + OFF_PROJV, ge0, ge1, ge1, wm, wn, w, lane);
        if (tid < BT) {
            float gq = (gx0[tid] + ge0[tid]) * sh_cos[tid] - (gx1[tid] + ge1[tid]) * sh_sin[tid];
            float gp = gx2[tid];
            float dq = M00 * gq + M01 * gp;
            float dp = M10 * gq + M11 * gp + buv;
            float wgt = (s == 0 || s == 3) ? 1.f : 2.f;
            aq += wgt * dq; ap += wgt * dp;
            if (s < 3) {
                float cs = (s == 2) ? 1.f : 0.5f;
                float qs = fmaf(cs * DTC, dq, q0);
                float ps = fmaf(cs * DTC, dp, p0);
                float sn, cn; __sincosf(qs, &sn, &cn);
                sh_sin[tid] = sn; sh_cos[tid] = cn; sh_pv[tid] = ps;
            } else {
                float qn = fmaf(DTC / 6.f, aq, q0);
                float pn = fmaf(DTC / 6.f, ap, p0);
                ((float2*)out)[base + tid] = make_float2(qn, pn);
            }
        }
        __syncthreads();
    }
}

extern "C" void kernel_launch(void* const* d_in, const int* in_sizes, int n_in,
                              void* d_out, int out_size, void* d_ws, size_t ws_size,
                              hipStream_t stream) {
    const float* q    = (const float*)d_in[0];
    const float* p    = (const float*)d_in[1];
    const float* u    = (const float*)d_in[2];
    const float* kW1  = (const float*)d_in[3];
    const float* kb1  = (const float*)d_in[4];
    const float* kW2  = (const float*)d_in[5];
    const float* kb2  = (const float*)d_in[6];
    const float* kW3  = (const float*)d_in[7];
    const float* pW1  = (const float*)d_in[9];
    const float* pb1  = (const float*)d_in[10];
    const float* pW2  = (const float*)d_in[11];
    const float* pb2  = (const float*)d_in[12];
    const float* pW3  = (const float*)d_in[13];
    const float* A    = (const float*)d_in[15];
    const float* Lp   = (const float*)d_in[16];
    const float* bctl = (const float*)d_in[17];
    unsigned short* ws = (unsigned short*)d_ws;
    float* out = (float*)d_out;
    int B = in_sizes[0];

    prepack_kernel<<<(TOTAL_PRE + 255) / 256, 256, 0, stream>>>(kW1, kW2, pW1, pW2, ws);
    phgn_kernel<<<B / BT, 1024, 0, stream>>>(q, p, u, kW1, kb1, kb2, kW3,
                                             pW1, pb1, pb2, pW3, A, Lp, bctl, ws, out);
}

// Round 14
// 663.600 us; speedup vs baseline: 1.7523x; 1.2164x over previous
//
#include <hip/hip_runtime.h>

#define HID 256
#define BT 64
#define DTC 0.05f

typedef __attribute__((ext_vector_type(4))) float f32x4;
typedef __attribute__((ext_vector_type(8))) __bf16 bf16x8;

__device__ __forceinline__ unsigned cvt_pk_bf16(float lo, float hi) {
    unsigned r;
    asm("v_cvt_pk_bf16_f32 %0, %1, %2" : "=v"(r) : "v"(lo), "v"(hi));
    return r;
}

__device__ __forceinline__ unsigned short f2bf(float f) {
    unsigned int x = __float_as_uint(f);
    x += 0x7fffu + ((x >> 16) & 1u);
    return (unsigned short)(x >> 16);
}

__device__ __forceinline__ float sgpr_f(float v) {
    return __uint_as_float(__builtin_amdgcn_readfirstlane(__float_as_uint(v)));
}

// ---------------- prepack: fragment-linearized bf16 weight buffers ----------------
// k-order PERMUTED to match the interleaved LDS column layout: within each
// 32-wide k-block, physical slot p holds logical k = (p&1)*16 + (p>>1).
// (k is a reduction index: any permutation is valid as long as the LDS
// activation layout and the B-fragment k-order agree.)
#define OFF_FWDT 0         // [nt16][kk8][lane64][j8] : B[k][n]=kW2[n][k]  (fwd: a2 = h1 @ kW2^T)
#define OFF_BWDT 65536     // B[k][n]=kW2[k][n]                            (bwd: d1 = s2 @ kW2)
#define OFF_FWDV 131072
#define OFF_BWDV 196608
#define OFF_PROJT 262144   // [kk8][lane64][j8] : B[k][c]=kW1[k][c], c<3 else 0
#define OFF_PROJV 266240
#define TOTAL_PRE 270336

__global__ void prepack_kernel(const float* __restrict__ kW1, const float* __restrict__ kW2,
                               const float* __restrict__ pW1, const float* __restrict__ pW2,
                               unsigned short* __restrict__ ws) {
    int t = blockIdx.x * 256 + threadIdx.x;
    if (t >= TOTAL_PRE) return;
    float v;
    if (t < OFF_FWDV) {               // kW2 fwd/bwd
        int tt = t & 65535;
        bool bwd = t >= OFF_BWDT;
        int j = tt & 7, lane = (tt >> 3) & 63, kk = (tt >> 9) & 7, nt = tt >> 12;
        int n = nt * 16 + (lane & 15);
        int p = (lane >> 4) * 8 + j;
        int k = kk * 32 + ((p & 1) << 4) + (p >> 1);   // interleave perm
        v = bwd ? kW2[k * HID + n] : kW2[n * HID + k];
    } else if (t < OFF_PROJT) {       // pW2 fwd/bwd
        int tt = (t - OFF_FWDV) & 65535;
        bool bwd = t >= OFF_BWDV;
        int j = tt & 7, lane = (tt >> 3) & 63, kk = (tt >> 9) & 7, nt = tt >> 12;
        int n = nt * 16 + (lane & 15);
        int p = (lane >> 4) * 8 + j;
        int k = kk * 32 + ((p & 1) << 4) + (p >> 1);
        v = bwd ? pW2[k * HID + n] : pW2[n * HID + k];
    } else if (t < OFF_PROJV) {       // kW1 projection (N=3 padded to 16)
        int tt = t - OFF_PROJT;
        int j = tt & 7, lane = (tt >> 3) & 63, kk = tt >> 9;
        int c = lane & 15;
        int p = (lane >> 4) * 8 + j;
        int k = kk * 32 + ((p & 1) << 4) + (p >> 1);
        v = (c < 3) ? kW1[k * 3 + c] : 0.f;
    } else {                          // pW1 projection (N=2 padded to 16)
        int tt = t - OFF_PROJV;
        int j = tt & 7, lane = (tt >> 3) & 63, kk = tt >> 9;
        int c = lane & 15;
        int p = (lane >> 4) * 8 + j;
        int k = kk * 32 + ((p & 1) << 4) + (p >> 1);
        v = (c < 2) ? pW1[k * 2 + c] : 0.f;
    }
    ws[t] = f2bf(v);
}

// ---------------- fused main kernel ----------------
// R10 structure (best: 706us, spill-free): 512 threads = 8 waves, 64 samples/block,
// wave w owns cols [w*32,w*32+32) -> acc[4][2] (32 AGPR), __launch_bounds__(512,2),
// persistent NetRegs, s1p[16] packed sigma(a1), pre-barrier kk=0 B prefetch.
// NEW vs R10 (VALU/LDS-op reduction at identical structure):
//  - interleaved LDS col order (2l+t <-> t*16+l within each wave's 32-col block):
//    each lane's two C-fragment cols become ADJACENT -> phases 1/3/5 store ONE
//    b32 (the cvt_pk word) instead of two b16 + extracts. Prepack k-order matches.
//  - phase-1 sin/cos/pv read as f32x4 (4 rows at once): 48 -> 12 LDS reads.
// MFMA fragment layouts unchanged (verified r1-13, absmax 1.6e-2).
//   A: lane holds A[m=lane&15][k=(lane>>4)*8 + j]   (k now in physical order)
//   B: lane holds B[k=(lane>>4)*8 + j][n=lane&15]
//   C: lane reg r holds C[m=(lane>>4)*4 + r][n=lane&15]

#define MFMA __builtin_amdgcn_mfma_f32_16x16x32_bf16

struct NetRegs { float w0[2], w1[2], w2[2], b1[2], b2[2], w3[2]; };

template <int IND, int NOUT>
__device__ __forceinline__ void run_net(
    char* bufAc, char* bufBc,
    const float* sh_sin, const float* sh_cos, const float* sh_pv,
    const NetRegs& R,
    const unsigned short* __restrict__ fwdB, const unsigned short* __restrict__ bwdB,
    const unsigned short* __restrict__ projB,
    float* g0, float* g1, float* g2,
    int w, int lane)
{
    const int lr = lane & 15;
    const int lg = lane >> 4;
    const unsigned int arx = (unsigned)(lr & 7) << 4;
    const unsigned int cbase = ((unsigned)lg << 4) ^ arx;
    const unsigned int colb = (unsigned)(w * 64 + lr * 4);   // physical byte of this lane's col pair

    unsigned s1p[16];   // packed bf16 sigma(a1), index mt*4+r

    // ---- phase 1: a1 = W1·x + b1 ; h1 = softplus -> bufA (b32) ; sigma -> s1p ----
#pragma unroll
    for (int mt = 0; mt < 4; ++mt) {
        int r0 = mt * 16 + lg * 4;
        f32x4 sv4 = *(const f32x4*)&sh_sin[r0];
        f32x4 cv4 = *(const f32x4*)&sh_cos[r0];
        f32x4 pv4 = *(const f32x4*)&sh_pv[r0];
#pragma unroll
        for (int r = 0; r < 4; ++r) {
            int row = r0 + r;
            float sv = sv4[r], cv = cv4[r];
            float pv = (IND == 3) ? pv4[r] : 0.f;
            float sp[2], sg[2];
#pragma unroll
            for (int nt = 0; nt < 2; ++nt) {
                float x = fmaf(R.w0[nt], sv, R.b1[nt]);
                x = fmaf(R.w1[nt], cv, x);
                if (IND == 3) x = fmaf(R.w2[nt], pv, x);
                float e = __expf(-fabsf(x));
                sp[nt] = fmaxf(x, 0.f) + __logf(1.f + e);
                float t = __builtin_amdgcn_rcpf(1.f + e);
                sg[nt] = (x < 0.f) ? e * t : t;
            }
            unsigned dsp = cvt_pk_bf16(sp[0], sp[1]);
            s1p[mt * 4 + r] = cvt_pk_bf16(sg[0], sg[1]);
            *(unsigned*)(bufAc + row * 512 + (colb ^ ((unsigned)(row & 7) << 4))) = dsp;
        }
    }

    // prefetch kk=0 fwd B-fragments (global, no LDS dependency) before barrier
    const unsigned short* fb = fwdB + (w * 2) * 8 * 512 + lane * 8;
    bf16x8 c0 = *(const bf16x8*)(fb + 0 * 512);
    bf16x8 c1 = *(const bf16x8*)(fb + 8 * 512);
    __syncthreads();   // h1 visible

    // ---- phase 2: fwd GEMM  acc = H1 @ W2^T  (reads bufA) ----
    f32x4 acc[4][2];
#pragma unroll
    for (int mt = 0; mt < 4; ++mt)
#pragma unroll
        for (int nt = 0; nt < 2; ++nt)
            acc[mt][nt] = (f32x4){0.f, 0.f, 0.f, 0.f};
    {
#pragma unroll 1
        for (int kk = 0; kk < 8; ++kk) {
            unsigned int off = cbase ^ (unsigned)(kk << 6);
            bf16x8 af0 = *(const bf16x8*)(bufAc + (0 * 16 + lr) * 512 + off);
            bf16x8 af1 = *(const bf16x8*)(bufAc + (1 * 16 + lr) * 512 + off);
            bf16x8 af2 = *(const bf16x8*)(bufAc + (2 * 16 + lr) * 512 + off);
            bf16x8 af3 = *(const bf16x8*)(bufAc + (3 * 16 + lr) * 512 + off);
            acc[0][0] = MFMA(af0, c0, acc[0][0], 0, 0, 0);
            acc[0][1] = MFMA(af0, c1, acc[0][1], 0, 0, 0);
            acc[1][0] = MFMA(af1, c0, acc[1][0], 0, 0, 0);
            acc[1][1] = MFMA(af1, c1, acc[1][1], 0, 0, 0);
            acc[2][0] = MFMA(af2, c0, acc[2][0], 0, 0, 0);
            acc[2][1] = MFMA(af2, c1, acc[2][1], 0, 0, 0);
            acc[3][0] = MFMA(af3, c0, acc[3][0], 0, 0, 0);
            acc[3][1] = MFMA(af3, c1, acc[3][1], 0, 0, 0);
            if (kk < 7) {
                c0 = *(const bf16x8*)(fb + (0 * 8 + kk + 1) * 512);
                c1 = *(const bf16x8*)(fb + (1 * 8 + kk + 1) * 512);
            }
        }
    }

    // ---- phase 3: s2 = W3 ⊙ σ(a2 + b2) -> bufB (b32 stores) ----
#pragma unroll
    for (int mt = 0; mt < 4; ++mt) {
#pragma unroll
        for (int r = 0; r < 4; ++r) {
            float x0 = acc[mt][0][r] + R.b2[0];
            float x1 = acc[mt][1][r] + R.b2[1];
            float e0 = __expf(-fabsf(x0));
            float t0 = __builtin_amdgcn_rcpf(1.f + e0);
            float s0 = (x0 < 0.f) ? e0 * t0 : t0;
            float e1 = __expf(-fabsf(x1));
            float t1 = __builtin_amdgcn_rcpf(1.f + e1);
            float s1 = (x1 < 0.f) ? e1 * t1 : t1;
            unsigned d = cvt_pk_bf16(R.w3[0] * s0, R.w3[1] * s1);
            int row = mt * 16 + lg * 4 + r;
            *(unsigned*)(bufBc + row * 512 + (colb ^ ((unsigned)(row & 7) << 4))) = d;
        }
    }

    // prefetch kk=0 bwd B-fragments before barrier
    const unsigned short* bb = bwdB + (w * 2) * 8 * 512 + lane * 8;
    c0 = *(const bf16x8*)(bb + 0 * 512);
    c1 = *(const bf16x8*)(bb + 8 * 512);
    __syncthreads();   // s2 visible

    // ---- phase 4: bwd GEMM  acc = S2 @ W2  (reads bufB) ----
#pragma unroll
    for (int mt = 0; mt < 4; ++mt)
#pragma unroll
        for (int nt = 0; nt < 2; ++nt)
            acc[mt][nt] = (f32x4){0.f, 0.f, 0.f, 0.f};
    {
#pragma unroll 1
        for (int kk = 0; kk < 8; ++kk) {
            unsigned int off = cbase ^ (unsigned)(kk << 6);
            bf16x8 af0 = *(const bf16x8*)(bufBc + (0 * 16 + lr) * 512 + off);
            bf16x8 af1 = *(const bf16x8*)(bufBc + (1 * 16 + lr) * 512 + off);
            bf16x8 af2 = *(const bf16x8*)(bufBc + (2 * 16 + lr) * 512 + off);
            bf16x8 af3 = *(const bf16x8*)(bufBc + (3 * 16 + lr) * 512 + off);
            acc[0][0] = MFMA(af0, c0, acc[0][0], 0, 0, 0);
            acc[0][1] = MFMA(af0, c1, acc[0][1], 0, 0, 0);
            acc[1][0] = MFMA(af1, c0, acc[1][0], 0, 0, 0);
            acc[1][1] = MFMA(af1, c1, acc[1][1], 0, 0, 0);
            acc[2][0] = MFMA(af2, c0, acc[2][0], 0, 0, 0);
            acc[2][1] = MFMA(af2, c1, acc[2][1], 0, 0, 0);
            acc[3][0] = MFMA(af3, c0, acc[3][0], 0, 0, 0);
            acc[3][1] = MFMA(af3, c1, acc[3][1], 0, 0, 0);
            if (kk < 7) {
                c0 = *(const bf16x8*)(bb + (0 * 8 + kk + 1) * 512);
                c1 = *(const bf16x8*)(bb + (1 * 8 + kk + 1) * 512);
            }
        }
    }

    // ---- phase 5: da1 = D1 ⊙ σ(a1) -> bufA (σ from s1p; single b32 store) ----
#pragma unroll
    for (int mt = 0; mt < 4; ++mt) {
#pragma unroll
        for (int r = 0; r < 4; ++r) {
            int row = mt * 16 + lg * 4 + r;
            unsigned pa = s1p[mt * 4 + r];
            float sg0 = __uint_as_float(pa << 16);
            float sg1 = __uint_as_float(pa & 0xffff0000u);
            unsigned d = cvt_pk_bf16(acc[mt][0][r] * sg0, acc[mt][1][r] * sg1);
            *(unsigned*)(bufAc + row * 512 + (colb ^ ((unsigned)(row & 7) << 4))) = d;
        }
    }
    __syncthreads();   // da1 visible

    // ---- phase 6: projection  g = dA1 @ W1  (waves 0-3, rows [w*16,w*16+16)) ----
    if (w < 4) {
        const unsigned short* pb = projB + lane * 8;
        f32x4 pacc = (f32x4){0.f, 0.f, 0.f, 0.f};
        char* arow = bufAc + (w * 16 + lr) * 512;
#pragma unroll 1
        for (int kk = 0; kk < 8; ++kk) {
            bf16x8 bv = *(const bf16x8*)(pb + kk * 512);
            bf16x8 af = *(const bf16x8*)(arow + (cbase ^ (unsigned)(kk << 6)));
            pacc = MFMA(af, bv, pacc, 0, 0, 0);
        }
        if (lr < NOUT) {
            float* dst = (lr == 0) ? g0 : ((lr == 1) ? g1 : g2);
#pragma unroll
            for (int r = 0; r < 4; ++r) dst[w * 16 + lg * 4 + r] = pacc[r];
        }
    }
    __syncthreads();   // proj reads of bufA done; gradients visible
}

__global__ __launch_bounds__(512, 2) void phgn_kernel(
    const float* __restrict__ q, const float* __restrict__ p, const float* __restrict__ u,
    const float* __restrict__ kW1, const float* __restrict__ kb1,
    const float* __restrict__ kb2, const float* __restrict__ kW3,
    const float* __restrict__ pW1, const float* __restrict__ pb1,
    const float* __restrict__ pb2, const float* __restrict__ pW3,
    const float* __restrict__ A, const float* __restrict__ Lp, const float* __restrict__ bctrl,
    const unsigned short* __restrict__ ws, float* __restrict__ out)
{
    __shared__ __attribute__((aligned(16))) unsigned short bufA[BT * HID];
    __shared__ __attribute__((aligned(16))) unsigned short bufB[BT * HID];
    __shared__ __attribute__((aligned(16))) float sh_sin[BT];
    __shared__ __attribute__((aligned(16))) float sh_cos[BT];
    __shared__ __attribute__((aligned(16))) float sh_pv[BT];
    __shared__ float gx0[BT], gx1[BT], gx2[BT], ge0[BT], ge1[BT];

    const int tid = threadIdx.x;
    const int w = tid >> 6, lane = tid & 63;
    const int lr = lane & 15;
    const int base = blockIdx.x * BT;

    // Persistent per-thread weights (stage-invariant), loaded once.
    NetRegs RT, RV;
#pragma unroll
    for (int nt = 0; nt < 2; ++nt) {
        int j = w * 32 + nt * 16 + lr;
        RT.w0[nt] = kW1[j * 3 + 0];
        RT.w1[nt] = kW1[j * 3 + 1];
        RT.w2[nt] = kW1[j * 3 + 2];
        RT.b1[nt] = kb1[j];
        RT.b2[nt] = kb2[j];
        RT.w3[nt] = kW3[j];
        RV.w0[nt] = pW1[j * 2 + 0];
        RV.w1[nt] = pW1[j * 2 + 1];
        RV.w2[nt] = 0.f;
        RV.b1[nt] = pb1[j];
        RV.b2[nt] = pb2[j];
        RV.w3[nt] = pW3[j];
    }

    // M = (A - A^T) - L L^T (uniform; pinned to SGPR via readfirstlane)
    float l00 = __logf(1.f + __expf(Lp[0]));
    float l11 = __logf(1.f + __expf(Lp[3]));
    float l10 = Lp[2];
    float J01 = A[1] - A[2];
    float M00 = sgpr_f(-(l00 * l00));
    float M01 = sgpr_f(J01 - l00 * l10);
    float M10 = sgpr_f(-J01 - l10 * l00);
    float M11 = sgpr_f(-(l10 * l10 + l11 * l11));

    float q0 = 0.f, p0 = 0.f, buv = 0.f, aq = 0.f, ap = 0.f;
    if (tid < BT) {
        q0 = q[base + tid]; p0 = p[base + tid]; buv = u[base + tid] * bctrl[0];
        float s, c; __sincosf(q0, &s, &c);
        sh_sin[tid] = s; sh_cos[tid] = c; sh_pv[tid] = p0;
    }
    __syncthreads();

    char* bufAc = (char*)bufA;
    char* bufBc = (char*)bufB;
#pragma unroll 1
    for (int s = 0; s < 4; ++s) {
        run_net<3, 3>(bufAc, bufBc, sh_sin, sh_cos, sh_pv, RT,
                      ws + OFF_FWDT, ws + OFF_BWDT, ws + OFF_PROJT, gx0, gx1, gx2, w, lane);
        run_net<2, 2>(bufAc, bufBc, sh_sin, sh_cos, sh_pv, RV,
                      ws + OFF_FWDV, ws + OFF_BWDV, ws + OFF_PROJV, ge0, ge1, ge1, w, lane);
        if (tid < BT) {
            float gq = (gx0[tid] + ge0[tid]) * sh_cos[tid] - (gx1[tid] + ge1[tid]) * sh_sin[tid];
            float gp = gx2[tid];
            float dq = M00 * gq + M01 * gp;
            float dp = M10 * gq + M11 * gp + buv;
            float wgt = (s == 0 || s == 3) ? 1.f : 2.f;
            aq += wgt * dq; ap += wgt * dp;
            if (s < 3) {
                float cs = (s == 2) ? 1.f : 0.5f;
                float qs = fmaf(cs * DTC, dq, q0);
                float ps = fmaf(cs * DTC, dp, p0);
                float sn, cn; __sincosf(qs, &sn, &cn);
                sh_sin[tid] = sn; sh_cos[tid] = cn; sh_pv[tid] = ps;
            } else {
                float qn = fmaf(DTC / 6.f, aq, q0);
                float pn = fmaf(DTC / 6.f, ap, p0);
                ((float2*)out)[base + tid] = make_float2(qn, pn);
            }
        }
        __syncthreads();
    }
}

extern "C" void kernel_launch(void* const* d_in, const int* in_sizes, int n_in,
                              void* d_out, int out_size, void* d_ws, size_t ws_size,
                              hipStream_t stream) {
    const float* q    = (const float*)d_in[0];
    const float* p    = (const float*)d_in[1];
    const float* u    = (const float*)d_in[2];
    const float* kW1  = (const float*)d_in[3];
    const float* kb1  = (const float*)d_in[4];
    const float* kW2  = (const float*)d_in[5];
    const float* kb2  = (const float*)d_in[6];
    const float* kW3  = (const float*)d_in[7];
    const float* pW1  = (const float*)d_in[9];
    const float* pb1  = (const float*)d_in[10];
    const float* pW2  = (const float*)d_in[11];
    const float* pb2  = (const float*)d_in[12];
    const float* pW3  = (const float*)d_in[13];
    const float* A    = (const float*)d_in[15];
    const float* Lp   = (const float*)d_in[16];
    const float* bctl = (const float*)d_in[17];
    unsigned short* ws = (unsigned short*)d_ws;
    float* out = (float*)d_out;
    int B = in_sizes[0];

    prepack_kernel<<<(TOTAL_PRE + 255) / 256, 256, 0, stream>>>(kW1, kW2, pW1, pW2, ws);
    phgn_kernel<<<B / BT, 512, 0, stream>>>(q, p, u, kW1, kb1, kb2, kW3,
                                            pW1, pb1, pb2, pW3, A, Lp, bctl, ws, out);
}